// Round 1
// baseline (462.013 us; speedup 1.0000x reference)
//
#include <hip/hip_runtime.h>
#include <math.h>

// Problem: IN=8192, HID=8192, OUT=1024, all fp32.
// out[o] = spiking_layer(spiking_layer(exp(x), W1), W2)[o]
// Key reduction: mismatch predicate is monotone in sorted-z order, so the
// per-row scan collapses to a binary search; Wc is a prefix (or suffix) sum
// of the W row in sorted-z column order.

#define NSZ 8192

__global__ void exp_kernel(const float* __restrict__ x, float* __restrict__ z, int n) {
    int i = blockIdx.x * blockDim.x + threadIdx.x;
    if (i < n) z[i] = expf(x[i]);
}

// One block per row; rows [0,rows1) from W1 -> Wsum1, rows [rows1, rows1+rows2) from W2 -> Wsum2.
// Both matrices have `cols` columns. Memory-bound: reads all of W once.
__global__ void rowsum_kernel(const float* __restrict__ W1, int rows1,
                              const float* __restrict__ W2, int rows2,
                              float* __restrict__ Wsum1, float* __restrict__ Wsum2,
                              int cols) {
    int r = blockIdx.x;
    const float* W;
    float* outp;
    int row;
    if (r < rows1) { W = W1; outp = Wsum1; row = r; }
    else           { W = W2; outp = Wsum2; row = r - rows1; }
    const float4* Wrow = (const float4*)(W + (size_t)row * cols);
    int n4 = cols >> 2;
    float s = 0.f;
    for (int i = threadIdx.x; i < n4; i += blockDim.x) {
        float4 v = Wrow[i];
        s += (v.x + v.y) + (v.z + v.w);
    }
    __shared__ float red[8];
    for (int off = 32; off > 0; off >>= 1) s += __shfl_down(s, off);
    int lane = threadIdx.x & 63, wv = threadIdx.x >> 6;
    if (lane == 0) red[wv] = s;
    __syncthreads();
    if (threadIdx.x == 0) {
        float t = 0.f;
        int nw = blockDim.x >> 6;
        for (int w = 0; w < nw; ++w) t += red[w];
        outp[row] = t;
    }
}

// Brute-force stable rank: rank[j] = #{j' : z[j'] < z[j] || (z[j']==z[j] && j'<j)}
// grid = (n/256, TJ); block (bi,bj) compares j in [bi*256, ...) against chunk bj.
__global__ void rank_kernel(const float* __restrict__ z, int* __restrict__ rank, int n) {
    __shared__ float zt[1024];
    const int CHUNK = n / gridDim.y;   // 1024 when TJ=8
    int j = blockIdx.x * blockDim.x + threadIdx.x;
    float zj = z[j];
    int jpbase = blockIdx.y * CHUNK;
    for (int i = threadIdx.x; i < CHUNK; i += blockDim.x) zt[i] = z[jpbase + i];
    __syncthreads();
    int cnt = 0;
#pragma unroll 4
    for (int i = 0; i < CHUNK; ++i) {
        float zv = zt[i];
        int jp = jpbase + i;
        cnt += (zv < zj || (zv == zj && jp < j)) ? 1 : 0;
    }
    atomicAdd(&rank[j], cnt);
}

__global__ void scatter_kernel(const float* __restrict__ z, const int* __restrict__ rank,
                               float* __restrict__ zs, int* __restrict__ idx, int n) {
    int j = blockIdx.x * blockDim.x + threadIdx.x;
    if (j < n) {
        int r = rank[j];
        zs[r] = z[j];
        idx[r] = j;
    }
}

// Single block, 1024 threads, n = 8192 (8 elems/thread). Exclusive prefix:
// csZ[i] = sum of zs[0..i-1], csZ[0]=0, csZ[n]=total.
__global__ void scan_kernel(const float* __restrict__ zs, float* __restrict__ csZ, int n) {
    __shared__ float part[1024];
    int tid = threadIdx.x;
    const int per = 8;
    int base = tid * per;
    float v[per];
    float s = 0.f;
#pragma unroll
    for (int i = 0; i < per; ++i) { v[i] = zs[base + i]; s += v[i]; }
    part[tid] = s;
    __syncthreads();
    for (int off = 1; off < 1024; off <<= 1) {
        float t = (tid >= off) ? part[tid - off] : 0.f;
        __syncthreads();
        part[tid] += t;
        __syncthreads();
    }
    float run = part[tid] - s;   // exclusive base for this thread
#pragma unroll
    for (int i = 0; i < per; ++i) { csZ[base + i] = run; run += v[i]; }
    if (tid == 1023) csZ[n] = run;
}

// One block per output row. Compute k via the monotone-predicate reduction,
// then Wc via gather over the cheaper of {first k, last n-k} sorted columns.
__global__ void finalize_kernel(const float* __restrict__ W,
                                const float* __restrict__ Wsum_arr,
                                const float* __restrict__ zs,
                                const int* __restrict__ idx,
                                const float* __restrict__ csZ, int n,
                                float* __restrict__ out) {
    int o = blockIdx.x;
    __shared__ int sk;
    __shared__ int smode;   // 0 = empty (inf), 1 = forward gather, 2 = backward gather
    __shared__ float sred[8];
    if (threadIdx.x == 0) {
        float Wsum = Wsum_arr[o];
        float Zsum = csZ[n];
        float tmp = Wsum * Zsum / (Wsum - 1.0f);
        bool fc = Wsum > 1.0f;
        int k = 0;
        bool empty = false;
        if (fc) {
            // mismatch[i] = (zs[i] <= tmp): first true at 0 iff zs[0] <= tmp
            if (zs[0] <= tmp) k = n - 1; else empty = true;
        } else {
            // mismatch[i] = (zs[i] > tmp): any iff zs[n-1] > tmp
            if (tmp < zs[n - 1]) {
                int lo = 0, hi = n;               // c = #{i : zs[i] <= tmp}
                while (lo < hi) {
                    int mid = (lo + hi) >> 1;
                    if (zs[mid] <= tmp) lo = mid + 1; else hi = mid;
                }
                int c = lo;                       // i_star = c
                if (c == 0) k = n - 1;
                else if (c == 1) empty = true;    // k==0 -> empty
                else k = c - 1;
            } else empty = true;
        }
        sk = k;
        smode = empty ? 0 : ((2 * k <= n) ? 1 : 2);
    }
    __syncthreads();
    int mode = smode;
    if (mode == 0) {
        if (threadIdx.x == 0) out[o] = __builtin_inff();
        return;
    }
    int k = sk;
    const float* Wrow = W + (size_t)o * n;
    float part = 0.f;
    if (mode == 1) {
        for (int t = threadIdx.x; t < k; t += blockDim.x) part += Wrow[idx[t]];
    } else {
        for (int t = k + threadIdx.x; t < n; t += blockDim.x) part += Wrow[idx[t]];
    }
    for (int off = 32; off > 0; off >>= 1) part += __shfl_down(part, off);
    int lane = threadIdx.x & 63, wv = threadIdx.x >> 6;
    if (lane == 0) sred[wv] = part;
    __syncthreads();
    if (threadIdx.x == 0) {
        float S = 0.f;
        int nw = blockDim.x >> 6;
        for (int w = 0; w < nw; ++w) S += sred[w];
        float Wsum = Wsum_arr[o];
        float Wc = (mode == 1) ? S : (Wsum - S);
        float Zc = csZ[k];
        out[o] = Wc * Zc / (Wc - 1.0f);
    }
}

extern "C" void kernel_launch(void* const* d_in, const int* in_sizes, int n_in,
                              void* d_out, int out_size, void* d_ws, size_t ws_size,
                              hipStream_t stream) {
    const float* x  = (const float*)d_in[0];
    const float* W1 = (const float*)d_in[1];   // [8192, 8192]
    const float* W2 = (const float*)d_in[2];   // [1024, 8192]
    float* out = (float*)d_out;                // [1024]

    const int N = NSZ;           // both layers have 8192 input columns
    char* ws = (char*)d_ws;
    size_t off = 0;
    auto alloc = [&](size_t bytes) -> void* {
        void* p = ws + off;
        off += (bytes + 255) & ~(size_t)255;
        return p;
    };
    float* z1    = (float*)alloc((size_t)N * 4);
    float* zs1   = (float*)alloc((size_t)N * 4);
    float* csZ1  = (float*)alloc((size_t)(N + 1) * 4);
    float* Wsum1 = (float*)alloc((size_t)N * 4);
    float* z2    = (float*)alloc((size_t)N * 4);
    float* zs2   = (float*)alloc((size_t)N * 4);
    float* csZ2  = (float*)alloc((size_t)(N + 1) * 4);
    float* Wsum2 = (float*)alloc((size_t)1024 * 4);
    int* idx1    = (int*)alloc((size_t)N * 4);
    int* idx2    = (int*)alloc((size_t)N * 4);
    int* rank12  = (int*)alloc((size_t)2 * N * 4);   // rank1 | rank2, zeroed together
    int* rank1 = rank12;
    int* rank2 = rank12 + N;

    hipMemsetAsync(rank12, 0, (size_t)2 * N * 4, stream);

    exp_kernel<<<N / 256, 256, 0, stream>>>(x, z1, N);

    // Row sums of both matrices: the single mandatory full pass over W (288 MiB)
    rowsum_kernel<<<8192 + 1024, 256, 0, stream>>>(W1, 8192, W2, 1024, Wsum1, Wsum2, N);

    dim3 rgrid(N / 256, 8);
    // ---- layer 1 ----
    rank_kernel<<<rgrid, 256, 0, stream>>>(z1, rank1, N);
    scatter_kernel<<<N / 256, 256, 0, stream>>>(z1, rank1, zs1, idx1, N);
    scan_kernel<<<1, 1024, 0, stream>>>(zs1, csZ1, N);
    finalize_kernel<<<8192, 256, 0, stream>>>(W1, Wsum1, zs1, idx1, csZ1, N, z2);
    // ---- layer 2 ----
    rank_kernel<<<rgrid, 256, 0, stream>>>(z2, rank2, N);
    scatter_kernel<<<N / 256, 256, 0, stream>>>(z2, rank2, zs2, idx2, N);
    scan_kernel<<<1, 1024, 0, stream>>>(zs2, csZ2, N);
    finalize_kernel<<<1024, 256, 0, stream>>>(W2, Wsum2, zs2, idx2, csZ2, N, out);
}